// Round 4
// baseline (329.951 us; speedup 1.0000x reference)
//
#include <hip/hip_runtime.h>
#include <math.h>

#define HD 128
#define NNODE 8192
#define KNBR 8
#define NHS ((size_t)NNODE*(size_t)HD)

#define EPSF 1e-6f
#define PMX 0.9999f
#define ATHC (1.0f-1e-5f)
#define TANC 1.47079f

typedef unsigned short u16;
typedef unsigned int u32;
typedef __attribute__((ext_vector_type(8))) short short8;
typedef __attribute__((ext_vector_type(4))) float f32x4;

// ---------- fast hardware math ----------
static __device__ __forceinline__ float frcp(float x){ return __builtin_amdgcn_rcpf(x); }
static __device__ __forceinline__ float fdiv(float a,float b){ return a*__builtin_amdgcn_rcpf(b); }
static __device__ __forceinline__ float fsqrt(float x){ return __builtin_amdgcn_sqrtf(x); }
static __device__ __forceinline__ float fexp(float x){ return __builtin_amdgcn_exp2f(x*1.4426950408889634f); }
static __device__ __forceinline__ float flog(float x){ return __builtin_amdgcn_logf(x)*0.6931471805599453f; }
static __device__ __forceinline__ float ftanh(float x){
  float ax = fabsf(x);
  float e = fexp(-2.0f*ax);
  float t = (1.0f-e)*frcp(1.0f+e);
  return copysignf(t,x);
}
static __device__ __forceinline__ float fatanh(float x){
  x = fminf(fmaxf(x,-ATHC),ATHC);
  return 0.5f*flog((1.0f+x)*frcp(1.0f-x));
}
static __device__ __forceinline__ float fatan(float x){
  float ax = fabsf(x);
  bool inv = ax > 1.0f;
  float t = inv ? frcp(ax) : ax;
  float t2 = t*t;
  float p = -0.0117212f;
  p = p*t2 + 0.05265332f;
  p = p*t2 - 0.11643287f;
  p = p*t2 + 0.19354346f;
  p = p*t2 - 0.33262347f;
  p = p*t2 + 0.99997726f;
  float r = t*p;
  r = inv ? 1.5707963267948966f - r : r;
  return copysignf(r,x);
}
static __device__ __forceinline__ float ftan(float x){
  x = fminf(fmaxf(x,-TANC),TANC);
  float r = x*0.15915494309189535f;
  float s = __builtin_amdgcn_sinf(r);
  float c = __builtin_amdgcn_cosf(r);
  return s*frcp(c);
}
static __device__ __forceinline__ float sigm(float x){ return frcp(1.0f+fexp(-x)); }
static __device__ __forceinline__ float safeden(float d){
  return d>=0.0f ? fmaxf(d,EPSF) : fminf(d,-EPSF);
}

static __device__ __forceinline__ float wred(float v){
#pragma unroll
  for(int m=32;m;m>>=1) v += __shfl_xor(v,m,64);
  return v;
}
static __device__ __forceinline__ float hred16(float v){
#pragma unroll
  for(int m=8;m;m>>=1) v += __shfl_xor(v,m,64);
  return v;
}

// ---------- bf16 split ----------
static __device__ __forceinline__ u16 f2bf(float f){
  u32 u = __float_as_uint(f);
  u32 r = u + 0x7fffu + ((u>>16)&1u);
  return (u16)(r>>16);
}
static __device__ __forceinline__ float bf2f(u16 h){
  return __uint_as_float(((u32)h)<<16);
}
static __device__ __forceinline__ void split2(float v, u16* hp, u16* lp){
  u16 h = f2bf(v);
  float r = v - bf2f(h);
  *hp = h; *lp = f2bf(r);
}

// ---------------- workspace layout (units of NHS floats) ----------------
// R0..R8 : GEMM-A input bf16 planes (hi NHS u16 + lo NHS u16 per region):
//          xp1,xp2,xe(x),lh1,lh2,h3,lc1,lc2,c3   -- dead after GEMM-A,
//          reused as YP(R0-2), YS(R3-5), YE(R6-8) f32 (pitch 384)
// R9..R14 : S1,S2,S3,F1,F2,F3 f32 (GEMM-A out) -- dead after phaseB,
//           reused as LPbf(R9),LSbf(R10),LEbf(R11) bf16 planes + C1o(R12),C2o(R13),C3o(R14) f32
// R15..R17: CS1,CS2,CS3 f32
// R18..R20: XP,XS,XE f32
// R21..R23: H1P,H1S,H1E f32
// R24..R26: V1,V2,V3 f32
// scalars at 27*NHS: y2p(+0), y2s(+8192), d1(+16384), d2(+24576), c1n2(+32768), c2n2(+40960)
// weight bf16 planes at 27*NHS + 49152 (u32 area of 114688): hi[114688] u16 then lo[114688] u16
//   offsets (u16 in plane): Wq 0, Wc 16384, Uf 32768, Up 49152, Uiou 65536
#define SCOFF (27*NHS)
#define WOFF  (27*NHS + 49152)
#define NW    114688

// ---------------- kernel 0: weight split ----------------
__global__ __launch_bounds__(256) void k_wsplit(
  const float* __restrict__ Wq, const float* __restrict__ Wc,
  const float* __restrict__ Uf, const float* __restrict__ Up,
  const float* __restrict__ Uiou, float* __restrict__ ws)
{
  u16* WH = (u16*)(ws + WOFF);
  u16* WL = WH + NW;
  int idx0 = (blockIdx.x*256 + threadIdx.x)*4;
#pragma unroll
  for(int q=0;q<4;q++){
    int idx = idx0 + q;
    float v;
    if(idx < 16384)      v = Wq[idx];
    else if(idx < 32768) v = Wc[idx-16384];
    else if(idx < 49152) v = Uf[idx-32768];
    else if(idx < 65536) v = Up[idx-49152];
    else                 v = Uiou[idx-65536];
    split2(v, &WH[idx], &WL[idx]);
  }
}

// ---------------- kernel 1: per-row pre-transforms + bf16 split ----------------
__global__ __launch_bounds__(256) void k_pre(
    const float* __restrict__ x, const float* __restrict__ h1,
    const float* __restrict__ h2, const float* __restrict__ c1,
    const float* __restrict__ c2, const float* __restrict__ h3,
    const float* __restrict__ c3, float* __restrict__ ws)
{
  int row = blockIdx.x*4 + (threadIdx.x>>6);
  int l = threadIdx.x & 63;
  size_t i0 = (size_t)row*HD + l, i1 = i0 + 64;
  float xa=x[i0], xb=x[i1];
  float h1a=h1[i0], h1b=h1[i1];
  float h2a=h2[i0], h2b=h2[i1];
  float c1a=c1[i0], c1b=c1[i1];
  float c2a=c2[i0], c2b=c2[i1];
  float h3a=h3[i0], h3b=h3[i1];
  float c3a=c3[i0], c3b=c3[i1];
  float xsq = wred(xa*xa+xb*xb);
  float h1sq = wred(h1a*h1a+h1b*h1b);
  float h2sq = wred(h2a*h2a+h2b*h2b);
  float c1sq = wred(c1a*c1a+c1b*c1b);
  float c2sq = wred(c2a*c2a+c2b*c2b);
  size_t p0 = (size_t)row*HD + l, p1 = p0 + 64;
#define WRSPLIT(R, va, vb) { \
    u16* hp = (u16*)(ws + (size_t)(R)*NHS); u16* lp2 = hp + NHS; \
    split2(va, &hp[p0], &lp2[p0]); split2(vb, &hp[p1], &lp2[p1]); }
  float nx = fsqrt(xsq+1e-15f);
  {
    float t = ftanh(nx);
    float f = fminf(t,PMX)*frcp(nx);
    float ny = fsqrt(f*f*xsq + 1e-15f);
    float g = fatanh(ny)*frcp(ny) * f;
    WRSPLIT(0, g*xa, g*xb)
  }
  {
    float t = ftan(nx);
    float f = t*frcp(nx);
    float ny = fsqrt(f*f*xsq + 1e-15f);
    float g = fatan(ny)*frcp(ny) * f;
    WRSPLIT(1, g*xa, g*xb)
  }
  WRSPLIT(2, xa, xb)
  { float n=fsqrt(h1sq+1e-15f); float g=fatanh(n)*frcp(n); WRSPLIT(3, g*h1a, g*h1b) }
  { float n=fsqrt(h2sq+1e-15f); float g=fatan(n)*frcp(n);  WRSPLIT(4, g*h2a, g*h2b) }
  WRSPLIT(5, h3a, h3b)
  { float n=fsqrt(c1sq+1e-15f); float g=fatanh(n)*frcp(n); WRSPLIT(6, g*c1a, g*c1b) }
  { float n=fsqrt(c2sq+1e-15f); float g=fatan(n)*frcp(n);  WRSPLIT(7, g*c2a, g*c2b) }
  WRSPLIT(8, c3a, c3b)
#undef WRSPLIT
}

// ---------------- MFMA bf16x3 GEMM: out = post(in @ W^T + b) ----------------
enum { P_ID=0, P_EXP_P, P_EXP_S, P_SIG, P_TANH, P_SIG_LOG_P, P_SIG_LOG_S,
       P_LOGSIG_P, P_LOGSIG_S, P_TANH_EXP_P, P_TANH_EXP_S };

struct JobM { const u16* Ah; const u16* Al; const u16* Wh; const u16* Wl;
              const float* b; float* out; int pitch; int post; };
struct JobTabM { JobM j[12]; };

__global__ __launch_bounds__(256) void k_gemmM(JobTabM tab){
  JobM jb = tab.j[blockIdx.y];
  const int lane = threadIdx.x & 63;
  const int wave = threadIdx.x >> 6;
  const int nn = lane & 15, quad = lane >> 4;
  const int row0 = blockIdx.x*64 + wave*16;
  const u16* Ah = jb.Ah + (size_t)(row0+nn)*128 + quad*8;
  const u16* Al = jb.Al + (size_t)(row0+nn)*128 + quad*8;
  const u16* Wh = jb.Wh + (size_t)nn*128 + quad*8;
  const u16* Wl = jb.Wl + (size_t)nn*128 + quad*8;
  f32x4 acc[8];
#pragma unroll
  for(int t=0;t<8;t++) acc[t] = (f32x4){0.f,0.f,0.f,0.f};
#pragma unroll
  for(int kk=0;kk<4;kk++){
    short8 ah = *(const short8*)(Ah + kk*32);
    short8 al = *(const short8*)(Al + kk*32);
#pragma unroll
    for(int t=0;t<8;t++){
      short8 wh = *(const short8*)(Wh + t*2048 + kk*32);
      short8 wl = *(const short8*)(Wl + t*2048 + kk*32);
      acc[t] = __builtin_amdgcn_mfma_f32_16x16x32_bf16(ah, wh, acc[t], 0,0,0);
      acc[t] = __builtin_amdgcn_mfma_f32_16x16x32_bf16(al, wh, acc[t], 0,0,0);
      acc[t] = __builtin_amdgcn_mfma_f32_16x16x32_bf16(ah, wl, acc[t], 0,0,0);
    }
  }
  float bias[8];
#pragma unroll
  for(int t=0;t<8;t++) bias[t] = jb.b[t*16+nn];
#pragma unroll
  for(int r=0;r<4;r++){
    float v[8];
#pragma unroll
    for(int t=0;t<8;t++) v[t] = acc[t][r] + bias[t];
    float s2 = 0.f;
#pragma unroll
    for(int t=0;t<8;t++) s2 += v[t]*v[t];
    float nraw = hred16(s2);
    switch(jb.post){
      case P_ID: break;
      case P_EXP_P: {
        float n=fsqrt(nraw+1e-15f); float tt=ftanh(n); float f=fminf(tt,PMX)*frcp(n);
        for(int t=0;t<8;t++) v[t]*=f;
      } break;
      case P_EXP_S: {
        float n=fsqrt(nraw+1e-15f); float f=ftan(n)*frcp(n);
        for(int t=0;t<8;t++) v[t]*=f;
      } break;
      case P_SIG:
        for(int t=0;t<8;t++) v[t]=sigm(v[t]);
        break;
      case P_TANH:
        for(int t=0;t<8;t++) v[t]=ftanh(v[t]);
        break;
      case P_SIG_LOG_P: {
        float n=fsqrt(nraw+1e-15f); float tt=ftanh(n); float f=fminf(tt,PMX)*frcp(n);
        float z[8]; float zs=0.f;
        for(int t=0;t<8;t++){ z[t]=sigm(f*v[t]); zs+=z[t]*z[t]; }
        float zr=hred16(zs);
        float zn=fsqrt(zr+1e-15f);
        float g=fatanh(zn)*frcp(zn);
        for(int t=0;t<8;t++) v[t]=g*z[t];
      } break;
      case P_SIG_LOG_S: {
        float n=fsqrt(nraw+1e-15f); float f=ftan(n)*frcp(n);
        float z[8]; float zs=0.f;
        for(int t=0;t<8;t++){ z[t]=sigm(f*v[t]); zs+=z[t]*z[t]; }
        float zr=hred16(zs);
        float zn=fsqrt(zr+1e-15f);
        float g=fatan(zn)*frcp(zn);
        for(int t=0;t<8;t++) v[t]=g*z[t];
      } break;
      case P_LOGSIG_P: {
        float n=fsqrt(nraw+1e-15f); float tt=ftanh(n); float f=fminf(tt,PMX)*frcp(n);
        float ny=fsqrt(f*f*nraw+1e-15f);
        float g=fatanh(ny)*frcp(ny)*f;
        for(int t=0;t<8;t++) v[t]=sigm(g*v[t]);
      } break;
      case P_LOGSIG_S: {
        float n=fsqrt(nraw+1e-15f); float f=ftan(n)*frcp(n);
        float ny=fsqrt(f*f*nraw+1e-15f);
        float g=fatan(ny)*frcp(ny)*f;
        for(int t=0;t<8;t++) v[t]=sigm(g*v[t]);
      } break;
      case P_TANH_EXP_P: {
        float n=fsqrt(nraw+1e-15f); float tt=ftanh(n); float f=fminf(tt,PMX)*frcp(n);
        float ny=fsqrt(f*f*nraw+1e-15f);
        float g=fatanh(ny)*frcp(ny)*f;
        float T[8]; float Ts=0.f;
        for(int t=0;t<8;t++){ T[t]=ftanh(g*v[t]); Ts+=T[t]*T[t]; }
        float Tr=hred16(Ts);
        float Tn=fsqrt(Tr+1e-15f);
        float t2=ftanh(Tn); float f2=fminf(t2,PMX)*frcp(Tn);
        for(int t=0;t<8;t++) v[t]=f2*T[t];
      } break;
      case P_TANH_EXP_S: {
        float n=fsqrt(nraw+1e-15f); float f=ftan(n)*frcp(n);
        float ny=fsqrt(f*f*nraw+1e-15f);
        float g=fatan(ny)*frcp(ny)*f;
        float T[8]; float Ts=0.f;
        for(int t=0;t<8;t++){ T[t]=ftanh(g*v[t]); Ts+=T[t]*T[t]; }
        float Tr=hred16(Ts);
        float Tn=fsqrt(Tr+1e-15f);
        float f2=ftan(Tn)*frcp(Tn);
        for(int t=0;t<8;t++) v[t]=f2*T[t];
      } break;
    }
    float* orow = jb.out + (size_t)(row0 + quad*4 + r)*jb.pitch + nn;
#pragma unroll
    for(int t=0;t<8;t++) orow[t*16] = v[t];
  }
}

// ---------------- kernel 3: per-unique-node elementwise (phase B) ----------------
__global__ __launch_bounds__(256) void k_phaseB(
  const float* __restrict__ h1,const float* __restrict__ h2,const float* __restrict__ h3,
  const float* __restrict__ c1,const float* __restrict__ c2,const float* __restrict__ c3,
  const float* __restrict__ del_t, const float* __restrict__ dsc,
  float* __restrict__ ws)
{
  const float* S1 = ws+9*NHS;  const float* S2 = ws+10*NHS; const float* S3 = ws+11*NHS;
  const float* F1 = ws+12*NHS; const float* F2 = ws+13*NHS; const float* F3 = ws+14*NHS;
  const float* Q1 = ws+15*NHS; const float* Q2 = ws+16*NHS; const float* Q3 = ws+17*NHS;
  float* H1P = ws+21*NHS; float* H1S = ws+22*NHS; float* H1E = ws+23*NHS;
  float* V1 = ws+24*NHS;  float* V2 = ws+25*NHS;  float* V3 = ws+26*NHS;
  float* y2p = ws+SCOFF; float* y2s = y2p+8192; float* d1 = y2p+16384; float* d2 = y2p+24576;

  int j = blockIdx.x*4 + (threadIdx.x>>6);
  int l = threadIdx.x&63;
  size_t i0 = (size_t)j*HD+l, i1 = i0+64;
  float h1a=h1[i0],h1b=h1[i1], h2a=h2[i0],h2b=h2[i1], h3a=h3[i0],h3b=h3[i1];
  float c1a=c1[i0],c1b=c1[i1], c2a=c2[i0],c2b=c2[i1], c3a=c3[i0],c3b=c3[i1];
  float s1a=S1[i0],s1b=S1[i1], s2a=S2[i0],s2b=S2[i1], s3a=S3[i0],s3b=S3[i1];
  float f1a=F1[i0],f1b=F1[i1], f2a=F2[i0],f2b=F2[i1], f3a=F3[i0],f3b=F3[i1];
  float q1a=Q1[i0],q1b=Q1[i1], q2a=Q2[i0],q2b=Q2[i1], q3a=Q3[i0],q3b=Q3[i1];
  float g = fdiv(dsc[0], del_t[j]+1.0f);

  float h1sq = wred(h1a*h1a+h1b*h1b); float n1 = fsqrt(h1sq+1e-15f);
  float h2sq = wred(h2a*h2a+h2b*h2b); float n2 = fsqrt(h2sq+1e-15f);
  float h3sq = wred(h3a*h3a+h3b*h3b); float n3 = fsqrt(h3sq+1e-15f);
  float w1a=s1a*h1a, w1b=s1b*h1b;
  float w2a=s2a*h2a, w2b=s2b*h2b;
  float w3a=s3a*h3a, w3b=s3b*h3b;
  float w1sq = wred(w1a*w1a+w1b*w1b); float nw1 = fsqrt(w1sq+1e-15f);
  float w2sq = wred(w2a*w2a+w2b*w2b); float nw2 = fsqrt(w2sq+1e-15f);
  float w3sq = wred(w3a*w3a+w3b*w3b); float nw3 = fsqrt(w3sq+1e-15f);

  // ---- h_1p
  float t1 = ftanh(nw1*frcp(n1) * fatanh(n1));
  float fp1 = fminf(t1,PMX)*frcp(nw1); float np1 = fminf(t1,PMX);
  float nu2 = fatan(n2);
  float ne2 = fminf(ftanh(nu2),PMX);
  float t2 = ftanh(nw2*frcp(n2) * fatanh(ne2));
  float fp2 = fminf(t2,PMX)*frcp(nw2); float np2 = fminf(t2,PMX);
  float ne3 = fminf(ftanh(n3),PMX);
  float t3 = ftanh(nw3*frcp(n3) * fatanh(ne3));
  float fp3 = fminf(t3,PMX)*frcp(nw3); float np3 = fminf(t3,PMX);
  {
    float lamA = 2.0f*frcp(1.0f-np1*np1), lamB = 2.0f*frcp(1.0f-np2*np2), lamC = 2.0f*frcp(1.0f-np3*np3);
    float dn = frcp(fmaxf(fabsf(lamA+lamB+lamC-3.0f), EPSF));
    float va = (lamA*fp1*w1a + lamB*fp2*w2a + lamC*fp3*w3a)*dn;
    float vb = (lamA*fp1*w1b + lamB*fp2*w2b + lamC*fp3*w3b)*dn;
    float vsq = wred(va*va+vb*vb); float nv = fsqrt(vsq+1e-15f);
    float tt = ftanh(0.5f*fatanh(nv)); float ff = 3.0f*fminf(tt,PMX)*frcp(nv);
    H1P[i0]=ff*va; H1P[i1]=ff*vb;
    if(l==0) y2p[j] = ff*ff*vsq;
  }
  // ---- h_1s
  float t2s, fs2;
  {
    float nx1s = ftan(fatanh(n1));
    float t1s = ftanh(nw1*frcp(n1) * fatanh(nx1s));
    float fs1 = fminf(t1s,PMX)*frcp(nw1); float ns1 = fminf(t1s,PMX);
    t2s = ftan(nw2*frcp(n2) * fatan(n2));
    fs2 = t2s*frcp(nw2);
    float nx3s = ftan(n3);
    float t3s = ftan(nw3*frcp(n3) * fatan(nx3s));
    float fs3 = t3s*frcp(nw3);
    float lA = 2.0f*frcp(1.0f-ns1*ns1), lB = 2.0f*frcp(1.0f-t2s*t2s), lC = 2.0f*frcp(1.0f-t3s*t3s);
    float dns = frcp(fmaxf(fabsf(lA+lB+lC-3.0f), EPSF));
    float vsa = (lA*fs1*w1a + lB*fs2*w2a + lC*fs3*w3a)*dns;
    float vsb = (lA*fs1*w1b + lB*fs2*w2b + lC*fs3*w3b)*dns;
    float vssq = wred(vsa*vsa+vsb*vsb); float nvs = fsqrt(vssq+1e-15f);
    float tts = ftan(0.5f*fatan(nvs)); float ffs = 3.0f*tts*frcp(nvs);
    H1S[i0]=ffs*vsa; H1S[i1]=ffs*vsb;
    if(l==0) y2s[j] = ffs*ffs*vssq;
  }
  // ---- h_1e
  {
    float ne1 = fsqrt(fp1*fp1*w1sq + 1e-15f);
    float ge1 = fatanh(ne1)*frcp(ne1);
    float n2s_ = fsqrt(fs2*fs2*w2sq + 1e-15f);
    float ge2 = fatan(n2s_)*frcp(n2s_);
    H1E[i0] = ge1*fp1*w1a + ge2*fs2*w2a + s3a*h3a;
    H1E[i1] = ge1*fp1*w1b + ge2*fs2*w2b + s3b*h3b;
  }
  float ng = fsqrt(g*g+1e-15f);
  // ---- Poincare cell
  {
    float q1sq = wred(q1a*q1a+q1b*q1b);
    float c1rs = wred(c1a*c1a+c1b*c1b);
    float dq1 = wred(q1a*c1a+q1b*c1b);
    float xy = -dq1;
    float aa = 1.0f+2.0f*xy+c1rs, bb = 1.0f-q1sq;
    float dd = frcp(safeden(1.0f+2.0f*xy+q1sq*c1rs));
    float m1a = (aa*(-q1a)+bb*c1a)*dd, m1b = (aa*(-q1b)+bb*c1b)*dd;
    float m1sq = (aa*aa*q1sq + 2.0f*aa*bb*xy + bb*bb*c1rs)*dd*dd;
    float mdq = (-aa*q1sq + bb*dq1)*dd;
    { float nm = fsqrt(m1sq+1e-15f);
      if(nm>PMX){ float sc=PMX*frcp(nm); m1a*=sc; m1b*=sc; m1sq*=sc*sc; mdq*=sc; } }
    float nwg = fsqrt(g*g*q1sq+1e-15f);
    float tg = ftanh(nwg*frcp(ng) * fatanh(ng));
    float fX = fminf(tg,PMX)*frcp(nwg) * g;
    float X2sq = fX*fX*q1sq;
    float xy2 = fX*mdq;
    float a2 = 1.0f+2.0f*xy2+X2sq, b2 = 1.0f-m1sq;
    float d2d = frcp(safeden(1.0f+2.0f*xy2+m1sq*X2sq));
    float ka = (a2*m1a + b2*fX*q1a)*d2d, kb = (a2*m1b + b2*fX*q1b)*d2d;
    float ksq = (a2*a2*m1sq + 2.0f*a2*b2*xy2 + b2*b2*X2sq)*d2d*d2d;
    { float nk0 = fsqrt(ksq+1e-15f);
      if(nk0>PMX){ float sc=PMX*frcp(nk0); ka*=sc; kb*=sc; ksq*=sc*sc; } }
    float nk = fsqrt(ksq+1e-15f);
    float wfa = f1a*ka, wfb = f1b*kb;
    float wfsq = wred(wfa*wfa+wfb*wfb); float nwf = fsqrt(wfsq+1e-15f);
    float tu = ftanh(nwf*frcp(nk) * fatanh(nk));
    float fu = fminf(tu,PMX)*frcp(nwf);
    float u1sq = fu*fu*wfsq;
    float lam = 2.0f*frcp(1.0f-u1sq);
    V1[i0]=lam*fu*wfa; V1[i1]=lam*fu*wfb;
    if(l==0) d1[j]=lam-1.0f;
  }
  // ---- Sphere cell
  {
    float q2sq = wred(q2a*q2a+q2b*q2b);
    float c2rs = wred(c2a*c2a+c2b*c2b);
    float dq2 = wred(q2a*c2a+q2b*c2b);
    float xy = -dq2;
    float aa = 1.0f-2.0f*xy-c2rs, bb = 1.0f+q2sq;
    float dd = frcp(safeden(1.0f-2.0f*xy+q2sq*c2rs));
    float ma = (aa*(-q2a)+bb*c2a)*dd, mb = (aa*(-q2b)+bb*c2b)*dd;
    float msq = (aa*aa*q2sq + 2.0f*aa*bb*xy + bb*bb*c2rs)*dd*dd;
    float mdq = (-aa*q2sq + bb*dq2)*dd;
    float nwg = fsqrt(g*g*q2sq+1e-15f);
    float tg = ftan(nwg*frcp(ng) * fatan(ng));
    float fX = tg*frcp(nwg) * g;
    float X2sq = fX*fX*q2sq;
    float xy2 = fX*mdq;
    float a2 = 1.0f-2.0f*xy2-X2sq, b2 = 1.0f+msq;
    float d2d = frcp(safeden(1.0f-2.0f*xy2+msq*X2sq));
    float ka = (a2*ma + b2*fX*q2a)*d2d, kb = (a2*mb + b2*fX*q2b)*d2d;
    float ksq = (a2*a2*msq + 2.0f*a2*b2*xy2 + b2*b2*X2sq)*d2d*d2d;
    float nk = fsqrt(ksq+1e-15f);
    float wfa = f2a*ka, wfb = f2b*kb;
    float wfsq = wred(wfa*wfa+wfb*wfb); float nwf = fsqrt(wfsq+1e-15f);
    float tu = ftan(nwf*frcp(nk) * fatan(nk));
    float fu = tu*frcp(nwf);
    float u2sq = fu*fu*wfsq;
    float lam = 2.0f*frcp(1.0f+u2sq);
    V2[i0]=lam*fu*wfa; V2[i1]=lam*fu*wfb;
    if(l==0) d2[j]=lam-1.0f;
  }
  // ---- Euclid cell
  {
    float kea = c3a + q3a*(g-1.0f), keb = c3b + q3b*(g-1.0f);
    V3[i0]=f3a*kea; V3[i1]=f3b*keb;
  }
}

// ---------------- kernel 4: attention + K-reductions ----------------
__global__ __launch_bounds__(256) void k_attn(
  const int* __restrict__ nbr, float* __restrict__ ws)
{
  const float* XP = ws+18*NHS; const float* XS = ws+19*NHS; const float* XE = ws+20*NHS;
  const float* H1P = ws+21*NHS; const float* H1S = ws+22*NHS; const float* H1E = ws+23*NHS;
  const float* V1 = ws+24*NHS; const float* V2 = ws+25*NHS; const float* V3 = ws+26*NHS;
  u16* LPh = (u16*)(ws+9*NHS);  u16* LPl = LPh + NHS;
  u16* LSh = (u16*)(ws+10*NHS); u16* LSl = LSh + NHS;
  u16* LEh = (u16*)(ws+11*NHS); u16* LEl = LEh + NHS;
  float* C1o = ws+12*NHS; float* C2o = ws+13*NHS; float* C3o = ws+14*NHS;
  const float* y2p = ws+SCOFF; const float* y2s = y2p+8192;
  const float* d1 = y2p+16384; const float* d2 = y2p+24576;
  float* c1n2 = (float*)(y2p+32768); float* c2n2 = (float*)(y2p+40960);

  int n = blockIdx.x*4 + (threadIdx.x>>6);
  int l = threadIdx.x&63;
  size_t i0 = (size_t)n*HD+l, i1 = i0+64;
  float XPa=XP[i0], XPb=XP[i1];
  float XSa=XS[i0], XSb=XS[i1];
  float XEa=XE[i0], XEb=XE[i1];
  float x2p = wred(XPa*XPa+XPb*XPb);
  float x2s = wred(XSa*XSa+XSb*XSb);
  float HPa[8],HPb[8],HSa[8],HSb[8],HEa[8],HEb[8],y2pk[8],y2sk[8];
  float scp[8],scs[8],sce[8];
  float v1a=0,v1b=0,v2a=0,v2b=0,v3a=0,v3b=0,ds1=0,ds2=0;
  const float rs = 0.08838834764831845f;
#pragma unroll
  for(int k=0;k<8;k++){
    int j = nbr[n*KNBR+k];
    size_t j0 = (size_t)j*HD+l, j1 = j0+64;
    HPa[k]=H1P[j0]; HPb[k]=H1P[j1];
    HSa[k]=H1S[j0]; HSb[k]=H1S[j1];
    HEa[k]=H1E[j0]; HEb[k]=H1E[j1];
    y2pk[k]=y2p[j]; y2sk[k]=y2s[j];
    v1a+=V1[j0]; v1b+=V1[j1];
    v2a+=V2[j0]; v2b+=V2[j1];
    v3a+=V3[j0]; v3b+=V3[j1];
    ds1+=d1[j]; ds2+=d2[j];
    float dp = wred(XPa*HPa[k]+XPb*HPb[k]);
    {
      float xy=-dp, y2=y2pk[k];
      float aa=1.0f+2.0f*xy+y2, bb=1.0f-x2p;
      float dd=frcp(safeden(1.0f+2.0f*xy+x2p*y2));
      float nsq=(aa*aa*x2p+2.0f*aa*bb*xy+bb*bb*y2)*dd*dd;
      float nn=fminf(fsqrt(nsq+1e-15f),PMX);
      scp[k] = -2.0f*fatanh(nn);
    }
    float dsv = wred(XSa*HSa[k]+XSb*HSb[k]);
    {
      float xy=-dsv, y2=y2sk[k];
      float aa=1.0f-2.0f*xy-y2, bb=1.0f+x2s;
      float dd=frcp(safeden(1.0f-2.0f*xy+x2s*y2));
      float nsq=(aa*aa*x2s+2.0f*aa*bb*xy+bb*bb*y2)*dd*dd;
      float nn=fsqrt(nsq+1e-15f);
      scs[k] = -2.0f*fatan(nn);
    }
    sce[k] = wred(XEa*HEa[k]+XEb*HEb[k])*rs;
  }
  { // p attention + wmid
    float mx=scp[0];
#pragma unroll
    for(int k=1;k<8;k++) mx=fmaxf(mx,scp[k]);
    float a[8]; float s=0;
#pragma unroll
    for(int k=0;k<8;k++){ a[k]=fexp(scp[k]-mx); s+=a[k]; }
    float inv=frcp(s);
    float na=0,nb=0,de=0;
#pragma unroll
    for(int k=0;k<8;k++){
      float lam = 2.0f*frcp(1.0f-y2pk[k]); float w=a[k]*inv;
      na+=w*lam*HPa[k]; nb+=w*lam*HPb[k]; de+=w*(lam-1.0f);
    }
    de = frcp(fmaxf(fabsf(de),EPSF));
    na*=de; nb*=de;
    float vsq=wred(na*na+nb*nb); float nv=fsqrt(vsq+1e-15f);
    float tt=ftanh(0.5f*fatanh(nv)); float f=fminf(tt,PMX)*frcp(nv);
    float ha=f*na, hb=f*nb;
    float hn=fsqrt(f*f*vsq+1e-15f);
    float gl=fatanh(hn)*frcp(hn);
    split2(gl*ha, &LPh[i0], &LPl[i0]); split2(gl*hb, &LPh[i1], &LPl[i1]);
  }
  { // s attention + wmid
    float mx=scs[0];
#pragma unroll
    for(int k=1;k<8;k++) mx=fmaxf(mx,scs[k]);
    float a[8]; float s=0;
#pragma unroll
    for(int k=0;k<8;k++){ a[k]=fexp(scs[k]-mx); s+=a[k]; }
    float inv=frcp(s);
    float na=0,nb=0,de=0;
#pragma unroll
    for(int k=0;k<8;k++){
      float lam = 2.0f*frcp(1.0f+y2sk[k]); float w=a[k]*inv;
      na+=w*lam*HSa[k]; nb+=w*lam*HSb[k]; de+=w*(lam-1.0f);
    }
    de = frcp(fmaxf(fabsf(de),EPSF));
    na*=de; nb*=de;
    float vsq=wred(na*na+nb*nb); float nv=fsqrt(vsq+1e-15f);
    float tt=ftan(0.5f*fatan(nv)); float f=tt*frcp(nv);
    float ha=f*na, hb=f*nb;
    float hn=fsqrt(f*f*vsq+1e-15f);
    float gl=fatan(hn)*frcp(hn);
    split2(gl*ha, &LSh[i0], &LSl[i0]); split2(gl*hb, &LSh[i1], &LSl[i1]);
  }
  { // e attention
    float mx=sce[0];
#pragma unroll
    for(int k=1;k<8;k++) mx=fmaxf(mx,sce[k]);
    float a[8]; float s=0;
#pragma unroll
    for(int k=0;k<8;k++){ a[k]=fexp(sce[k]-mx); s+=a[k]; }
    float inv=frcp(s);
    float ha=0,hb=0;
#pragma unroll
    for(int k=0;k<8;k++){ float w=a[k]*inv; ha+=w*HEa[k]; hb+=w*HEb[k]; }
    split2(ha, &LEh[i0], &LEl[i0]); split2(hb, &LEh[i1], &LEl[i1]);
  }
  { // c_1
    float de=frcp(fmaxf(fabsf(ds1),EPSF));
    float na=v1a*de, nb=v1b*de;
    float vsq=wred(na*na+nb*nb); float nv=fsqrt(vsq+1e-15f);
    float tt=ftanh(0.5f*fatanh(nv)); float f=fminf(tt,PMX)*frcp(nv);
    C1o[i0]=f*na; C1o[i1]=f*nb;
    if(l==0) c1n2[n]=f*f*vsq;
  }
  { // c_2
    float de=frcp(fmaxf(fabsf(ds2),EPSF));
    float na=v2a*de, nb=v2b*de;
    float vsq=wred(na*na+nb*nb); float nv=fsqrt(vsq+1e-15f);
    float tt=ftan(0.5f*fatan(nv)); float f=tt*frcp(nv);
    C2o[i0]=f*na; C2o[i1]=f*nb;
    if(l==0) c2n2[n]=f*f*vsq;
  }
  C3o[i0]=v3a; C3o[i1]=v3b;
}

// ---------------- kernel 6: final epilogue ----------------
__global__ __launch_bounds__(256) void k_final(
  const float* __restrict__ iou1, const float* __restrict__ iou2,
  const float* __restrict__ iou3, float* __restrict__ ws,
  float* __restrict__ out)
{
  const float* YP = ws; const float* YS = ws+3*NHS; const float* YE = ws+6*NHS;
  const float* C1v = ws+12*NHS; const float* C2v = ws+13*NHS; const float* C3v = ws+14*NHS;
  const float* c1n2 = ws+SCOFF+32768; const float* c2n2 = ws+SCOFF+40960;
  int n = blockIdx.x*4 + (threadIdx.x>>6);
  int l = threadIdx.x&63;
  size_t b384 = (size_t)n*384 + l;
  size_t b128 = (size_t)n*HD + l;
  // ================= Poincare =================
  {
    float Y[6], I[6];
#pragma unroll
    for(int r=0;r<6;r++){ Y[r]=YP[b384+64*r]; I[r]=iou1[b384+64*r]; }
    float sy=0,si=0,sx=0;
#pragma unroll
    for(int r=0;r<6;r++){ sy+=Y[r]*Y[r]; si+=I[r]*I[r]; sx+=I[r]*Y[r]; }
    sy=wred(sy); si=wred(si); sx=wred(sx);
    float nY=fsqrt(sy+1e-15f);
    float te=ftanh(nY); float fE=fminf(te,PMX)*frcp(nY);
    float y2=fE*fE*sy, x2=si, xy=fE*sx;
    float aa=1.0f+2.0f*xy+y2, bb=1.0f-x2;
    float dd=frcp(safeden(1.0f+2.0f*xy+x2*y2));
    float nio[6];
#pragma unroll
    for(int r=0;r<6;r++) nio[r]=(aa*I[r]+bb*fE*Y[r])*dd;
    float nsq=(aa*aa*x2+2.0f*aa*bb*xy+bb*bb*y2)*dd*dd;
    { float nn=fsqrt(nsq+1e-15f);
      if(nn>PMX){ float sc=PMX*frcp(nn); for(int r=0;r<6;r++) nio[r]*=sc; } }
    float ci=wred(nio[0]*nio[0]+nio[1]*nio[1]); float ni=fsqrt(ci+1e-15f); float gi=fatanh(ni)*frcp(ni);
    float ip0=sigm(gi*nio[0]), ip1=sigm(gi*nio[1]);
    float co=wred(nio[2]*nio[2]+nio[3]*nio[3]); float no=fsqrt(co+1e-15f); float go=fatanh(no)*frcp(no);
    float op0=sigm(go*nio[2]), op1=sigm(go*nio[3]);
    float cu=wred(nio[4]*nio[4]+nio[5]*nio[5]); float nu=fsqrt(cu+1e-15f); float gu=fatanh(nu)*frcp(nu);
    float up0=ftanh(gu*nio[4]), up1=ftanh(gu*nio[5]);
    float usq=wred(up0*up0+up1*up1); float nx=fsqrt(usq+1e-15f);
    float wv0=ip0*up0, wv1=ip1*up1;
    float wsq=wred(wv0*wv0+wv1*wv1); float nwx=fsqrt(wsq+1e-15f);
    float tP=ftanh(nwx*frcp(nx)*fatanh(nx)); float fP=fminf(tP,PMX)*frcp(nwx);
    float P0=fP*wv0, P1=fP*wv1; float p2=fP*fP*wsq;
    float ca=C1v[b128], cb=C1v[b128+64];
    float y2c=c1n2[n];
    float xyc=wred(P0*ca+P1*cb);
    float a3=1.0f+2.0f*xyc+y2c, b3=1.0f-p2;
    float d3=frcp(safeden(1.0f+2.0f*xyc+p2*y2c));
    float nc0=(a3*P0+b3*ca)*d3, nc1_=(a3*P1+b3*cb)*d3;
    float ncsq=(a3*a3*p2+2.0f*a3*b3*xyc+b3*b3*y2c)*d3*d3;
    { float nn=fsqrt(ncsq+1e-15f);
      if(nn>PMX){ float sc=PMX*frcp(nn); nc0*=sc; nc1_*=sc; ncsq*=sc*sc; } }
    float nl=fsqrt(ncsq+1e-15f);
    float gL=fatanh(nl)*frcp(nl);
    float T0=ftanh(gL*nc0), T1=ftanh(gL*nc1_);
    float tsq=wred(T0*T0+T1*T1); float nT=fsqrt(tsq+1e-15f);
    float wo0=op0*T0, wo1=op1*T1;
    float osq=wred(wo0*wo0+wo1*wo1); float nwo=fsqrt(osq+1e-15f);
    float tH=ftanh(nwo*frcp(nT)*fatanh(nT)); float fH=fminf(tH,PMX)*frcp(nwo);
    out[0*NHS + b128]=fH*wo0; out[0*NHS + b128+64]=fH*wo1;
    out[1*NHS + b128]=nc0;    out[1*NHS + b128+64]=nc1_;
  }
  // ================= Sphere =================
  {
    float Y[6], I[6];
#pragma unroll
    for(int r=0;r<6;r++){ Y[r]=YS[b384+64*r]; I[r]=iou2[b384+64*r]; }
    float sy=0,si=0,sx=0;
#pragma unroll
    for(int r=0;r<6;r++){ sy+=Y[r]*Y[r]; si+=I[r]*I[r]; sx+=I[r]*Y[r]; }
    sy=wred(sy); si=wred(si); sx=wred(sx);
    float nY=fsqrt(sy+1e-15f);
    float te=ftan(nY); float fE=te*frcp(nY);
    float y2=fE*fE*sy, x2=si, xy=fE*sx;
    float aa=1.0f-2.0f*xy-y2, bb=1.0f+x2;
    float dd=frcp(safeden(1.0f-2.0f*xy+x2*y2));
    float nio[6];
#pragma unroll
    for(int r=0;r<6;r++) nio[r]=(aa*I[r]+bb*fE*Y[r])*dd;
    float ci=wred(nio[0]*nio[0]+nio[1]*nio[1]); float ni=fsqrt(ci+1e-15f); float gi=fatan(ni)*frcp(ni);
    float ip0=sigm(gi*nio[0]), ip1=sigm(gi*nio[1]);
    float co=wred(nio[2]*nio[2]+nio[3]*nio[3]); float no=fsqrt(co+1e-15f); float go=fatan(no)*frcp(no);
    float op0=sigm(go*nio[2]), op1=sigm(go*nio[3]);
    float cu=wred(nio[4]*nio[4]+nio[5]*nio[5]); float nu=fsqrt(cu+1e-15f); float gu=fatan(nu)*frcp(nu);
    float up0=ftanh(gu*nio[4]), up1=ftanh(gu*nio[5]);
    float usq=wred(up0*up0+up1*up1); float nx=fsqrt(usq+1e-15f);
    float wv0=ip0*up0, wv1=ip1*up1;
    float wsq=wred(wv0*wv0+wv1*wv1); float nwx=fsqrt(wsq+1e-15f);
    float tP=ftan(nwx*frcp(nx)*fatan(nx)); float fP=tP*frcp(nwx);
    float P0=fP*wv0, P1=fP*wv1; float p2=fP*fP*wsq;
    float ca=C2v[b128], cb=C2v[b128+64];
    float y2c=c2n2[n];
    float xyc=wred(P0*ca+P1*cb);
    float a3=1.0f-2.0f*xyc-y2c, b3=1.0f+p2;
    float d3=frcp(safeden(1.0f-2.0f*xyc+p2*y2c));
    float nc0=(a3*P0+b3*ca)*d3, nc1_=(a3*P1+b3*cb)*d3;
    float ncsq=(a3*a3*p2+2.0f*a3*b3*xyc+b3*b3*y2c)*d3*d3;
    float nl=fsqrt(ncsq+1e-15f);
    float gL=fatan(nl)*frcp(nl);
    float T0=ftanh(gL*nc0), T1=ftanh(gL*nc1_);
    float tsq=wred(T0*T0+T1*T1); float nT=fsqrt(tsq+1e-15f);
    float wo0=op0*T0, wo1=op1*T1;
    float osq=wred(wo0*wo0+wo1*wo1); float nwo=fsqrt(osq+1e-15f);
    float tH=ftan(nwo*frcp(nT)*fatan(nT)); float fH=tH*frcp(nwo);
    out[2*NHS + b128]=fH*wo0; out[2*NHS + b128+64]=fH*wo1;
    out[3*NHS + b128]=nc0;    out[3*NHS + b128+64]=nc1_;
  }
  // ================= Euclid =================
  {
    float Y[6], I[6];
#pragma unroll
    for(int r=0;r<6;r++){ Y[r]=YE[b384+64*r]; I[r]=iou3[b384+64*r]; }
    float n0=I[0]+Y[0], n1=I[1]+Y[1];
    float n2=I[2]+Y[2], n3=I[3]+Y[3];
    float n4=I[4]+Y[4], n5=I[5]+Y[5];
    float ie0=sigm(n0), ie1=sigm(n1);
    float oe0=sigm(n2), oe1=sigm(n3);
    float ue0=ftanh(n4), ue1=ftanh(n5);
    float ca=C3v[b128], cb=C3v[b128+64];
    float nc0=ie0*ue0+ca, nc1_=ie1*ue1+cb;
    out[4*NHS + b128]=oe0*ftanh(nc0); out[4*NHS + b128+64]=oe1*ftanh(nc1_);
    out[5*NHS + b128]=nc0;            out[5*NHS + b128+64]=nc1_;
  }
}

extern "C" void kernel_launch(void* const* d_in, const int* in_sizes, int n_in,
                              void* d_out, int out_size, void* d_ws, size_t ws_size,
                              hipStream_t stream)
{
  const float* x     = (const float*)d_in[0];
  const float* h1    = (const float*)d_in[1];
  const float* c1    = (const float*)d_in[2];
  const float* h2    = (const float*)d_in[3];
  const float* c2    = (const float*)d_in[4];
  const float* h3    = (const float*)d_in[5];
  const float* c3    = (const float*)d_in[6];
  const float* del_t = (const float*)d_in[7];
  const float* iou1  = (const float*)d_in[8];
  const float* iou2  = (const float*)d_in[9];
  const float* iou3  = (const float*)d_in[10];
  const float* Wq_w  = (const float*)d_in[11];
  const float* Wq_b  = (const float*)d_in[12];
  const float* Wc_w  = (const float*)d_in[13];
  const float* Wc_b  = (const float*)d_in[14];
  const float* Uf_w  = (const float*)d_in[15];
  const float* Uf_b  = (const float*)d_in[16];
  const float* Up_w  = (const float*)d_in[17];
  const float* Up_b  = (const float*)d_in[18];
  const float* Uiou_w= (const float*)d_in[19];
  const float* Uiou_b= (const float*)d_in[20];
  const float* dsc   = (const float*)d_in[21];
  const int*   nbr   = (const int*)d_in[22];
  float* out = (float*)d_out;
  float* ws  = (float*)d_ws;

  k_wsplit<<<112,256,0,stream>>>(Wq_w,Wc_w,Uf_w,Up_w,Uiou_w,ws);
  k_pre<<<2048,256,0,stream>>>(x,h1,h2,c1,c2,h3,c3,ws);

  u16* WH = (u16*)(ws + WOFF);
  u16* WL = WH + NW;
  const u16* Wqh = WH;           const u16* Wql = WL;
  const u16* Wch = WH + 16384;   const u16* Wcl = WL + 16384;
  const u16* Ufh = WH + 32768;   const u16* Ufl = WL + 32768;
  const u16* Uph = WH + 49152;   const u16* Upl = WL + 49152;
  const u16* UIh = WH + 65536;   const u16* UIl = WL + 65536;
#define APLANE(R) ((const u16*)(ws + (size_t)(R)*NHS)), ((const u16*)(ws + (size_t)(R)*NHS) + NHS)

  JobTabM A{};
  A.j[0]  = { APLANE(0), Wqh, Wql, Wq_b, ws+18*NHS, 128, P_EXP_P };      // XP
  A.j[1]  = { APLANE(1), Wqh, Wql, Wq_b, ws+19*NHS, 128, P_EXP_S };      // XS
  A.j[2]  = { APLANE(2), Wqh, Wql, Wq_b, ws+20*NHS, 128, P_ID };         // XE
  A.j[3]  = { APLANE(3), Uph, Upl, Up_b, ws+9*NHS,  128, P_SIG_LOG_P };  // S1
  A.j[4]  = { APLANE(4), Uph, Upl, Up_b, ws+10*NHS, 128, P_SIG_LOG_S };  // S2
  A.j[5]  = { APLANE(5), Uph, Upl, Up_b, ws+11*NHS, 128, P_SIG };        // S3
  A.j[6]  = { APLANE(3), Ufh, Ufl, Uf_b, ws+12*NHS, 128, P_LOGSIG_P };   // F1
  A.j[7]  = { APLANE(4), Ufh, Ufl, Uf_b, ws+13*NHS, 128, P_LOGSIG_S };   // F2
  A.j[8]  = { APLANE(5), Ufh, Ufl, Uf_b, ws+14*NHS, 128, P_SIG };        // F3
  A.j[9]  = { APLANE(6), Wch, Wcl, Wc_b, ws+15*NHS, 128, P_TANH_EXP_P }; // CS1
  A.j[10] = { APLANE(7), Wch, Wcl, Wc_b, ws+16*NHS, 128, P_TANH_EXP_S }; // CS2
  A.j[11] = { APLANE(8), Wch, Wcl, Wc_b, ws+17*NHS, 128, P_TANH };       // CS3
  k_gemmM<<<dim3(128,12),256,0,stream>>>(A);

  k_phaseB<<<2048,256,0,stream>>>(h1,h2,h3,c1,c2,c3,del_t,dsc,ws);
  k_attn<<<2048,256,0,stream>>>(nbr,ws);

  JobTabM B{};
  for(int ct=0; ct<3; ct++){
    B.j[0*3+ct] = { APLANE(9),  UIh + ct*16384, UIl + ct*16384, Uiou_b + ct*128, ws+0*NHS + ct*128, 384, P_ID };
    B.j[1*3+ct] = { APLANE(10), UIh + ct*16384, UIl + ct*16384, Uiou_b + ct*128, ws+3*NHS + ct*128, 384, P_ID };
    B.j[2*3+ct] = { APLANE(11), UIh + ct*16384, UIl + ct*16384, Uiou_b + ct*128, ws+6*NHS + ct*128, 384, P_ID };
  }
  k_gemmM<<<dim3(128,9),256,0,stream>>>(B);

  k_final<<<2048,256,0,stream>>>(iou1,iou2,iou3,ws,out);
}

// Round 6
// 282.039 us; speedup vs baseline: 1.1699x; 1.1699x over previous
//
#include <hip/hip_runtime.h>
#include <math.h>

#define HD 128
#define NNODE 8192
#define KNBR 8
#define NHS ((size_t)NNODE*(size_t)HD)

#define EPSF 1e-6f
#define PMX 0.9999f
#define ATHC (1.0f-1e-5f)
#define TANC 1.47079f

typedef unsigned short u16;
typedef unsigned int u32;
typedef __attribute__((ext_vector_type(8))) short short8;
typedef __attribute__((ext_vector_type(4))) float f32x4;

// ---------- fast hardware math ----------
static __device__ __forceinline__ float frcp(float x){ return __builtin_amdgcn_rcpf(x); }
static __device__ __forceinline__ float fdiv(float a,float b){ return a*__builtin_amdgcn_rcpf(b); }
static __device__ __forceinline__ float fsqrt(float x){ return __builtin_amdgcn_sqrtf(x); }
static __device__ __forceinline__ float fexp(float x){ return __builtin_amdgcn_exp2f(x*1.4426950408889634f); }
static __device__ __forceinline__ float flog(float x){ return __builtin_amdgcn_logf(x)*0.6931471805599453f; }
static __device__ __forceinline__ float ftanh(float x){
  float ax = fabsf(x);
  float e = fexp(-2.0f*ax);
  float t = (1.0f-e)*frcp(1.0f+e);
  return copysignf(t,x);
}
static __device__ __forceinline__ float fatanh(float x){
  x = fminf(fmaxf(x,-ATHC),ATHC);
  return 0.5f*flog((1.0f+x)*frcp(1.0f-x));
}
static __device__ __forceinline__ float fatan(float x){
  float ax = fabsf(x);
  bool inv = ax > 1.0f;
  float t = inv ? frcp(ax) : ax;
  float t2 = t*t;
  float p = -0.0117212f;
  p = p*t2 + 0.05265332f;
  p = p*t2 - 0.11643287f;
  p = p*t2 + 0.19354346f;
  p = p*t2 - 0.33262347f;
  p = p*t2 + 0.99997726f;
  float r = t*p;
  r = inv ? 1.5707963267948966f - r : r;
  return copysignf(r,x);
}
static __device__ __forceinline__ float ftan(float x){
  x = fminf(fmaxf(x,-TANC),TANC);
  float r = x*0.15915494309189535f;
  float s = __builtin_amdgcn_sinf(r);
  float c = __builtin_amdgcn_cosf(r);
  return s*frcp(c);
}
static __device__ __forceinline__ float sigm(float x){ return frcp(1.0f+fexp(-x)); }
static __device__ __forceinline__ float safeden(float d){
  return d>=0.0f ? fmaxf(d,EPSF) : fminf(d,-EPSF);
}

static __device__ __forceinline__ float wred(float v){
#pragma unroll
  for(int m=32;m;m>>=1) v += __shfl_xor(v,m,64);
  return v;
}
static __device__ __forceinline__ float hred16(float v){
#pragma unroll
  for(int m=8;m;m>>=1) v += __shfl_xor(v,m,64);
  return v;
}

// ---------- bf16 split ----------
static __device__ __forceinline__ u16 f2bf(float f){
  u32 u = __float_as_uint(f);
  u32 r = u + 0x7fffu + ((u>>16)&1u);
  return (u16)(r>>16);
}
static __device__ __forceinline__ float bf2f(u16 h){
  return __uint_as_float(((u32)h)<<16);
}
static __device__ __forceinline__ void split2(float v, u16* hp, u16* lp){
  u16 h = f2bf(v);
  float r = v - bf2f(h);
  *hp = h; *lp = f2bf(r);
}

// ---------------- workspace layout: see R4 (unchanged) ----------------
#define SCOFF (27*NHS)
#define WOFF  (27*NHS + 49152)
#define NW    114688

// ---------------- kernel 0: weight split ----------------
__global__ __launch_bounds__(256) void k_wsplit(
  const float* __restrict__ Wq, const float* __restrict__ Wc,
  const float* __restrict__ Uf, const float* __restrict__ Up,
  const float* __restrict__ Uiou, float* __restrict__ ws)
{
  u16* WH = (u16*)(ws + WOFF);
  u16* WL = WH + NW;
  int idx0 = (blockIdx.x*256 + threadIdx.x)*4;
#pragma unroll
  for(int q=0;q<4;q++){
    int idx = idx0 + q;
    float v;
    if(idx < 16384)      v = Wq[idx];
    else if(idx < 32768) v = Wc[idx-16384];
    else if(idx < 49152) v = Uf[idx-32768];
    else if(idx < 65536) v = Up[idx-49152];
    else                 v = Uiou[idx-65536];
    split2(v, &WH[idx], &WL[idx]);
  }
}

// ---------------- kernel 1: per-row pre-transforms + bf16 split ----------------
__global__ __launch_bounds__(256) void k_pre(
    const float* __restrict__ x, const float* __restrict__ h1,
    const float* __restrict__ h2, const float* __restrict__ c1,
    const float* __restrict__ c2, const float* __restrict__ h3,
    const float* __restrict__ c3, float* __restrict__ ws)
{
  int row = blockIdx.x*4 + (threadIdx.x>>6);
  int l = threadIdx.x & 63;
  size_t i0 = (size_t)row*HD + l, i1 = i0 + 64;
  float xa=x[i0], xb=x[i1];
  float h1a=h1[i0], h1b=h1[i1];
  float h2a=h2[i0], h2b=h2[i1];
  float c1a=c1[i0], c1b=c1[i1];
  float c2a=c2[i0], c2b=c2[i1];
  float h3a=h3[i0], h3b=h3[i1];
  float c3a=c3[i0], c3b=c3[i1];
  float xsq = wred(xa*xa+xb*xb);
  float h1sq = wred(h1a*h1a+h1b*h1b);
  float h2sq = wred(h2a*h2a+h2b*h2b);
  float c1sq = wred(c1a*c1a+c1b*c1b);
  float c2sq = wred(c2a*c2a+c2b*c2b);
  size_t p0 = (size_t)row*HD + l, p1 = p0 + 64;
#define WRSPLIT(R, va, vb) { \
    u16* hp = (u16*)(ws + (size_t)(R)*NHS); u16* lp2 = hp + NHS; \
    split2(va, &hp[p0], &lp2[p0]); split2(vb, &hp[p1], &lp2[p1]); }
  float nx = fsqrt(xsq+1e-15f);
  {
    float t = ftanh(nx);
    float f = fminf(t,PMX)*frcp(nx);
    float ny = fsqrt(f*f*xsq + 1e-15f);
    float g = fatanh(ny)*frcp(ny) * f;
    WRSPLIT(0, g*xa, g*xb)
  }
  {
    float t = ftan(nx);
    float f = t*frcp(nx);
    float ny = fsqrt(f*f*xsq + 1e-15f);
    float g = fatan(ny)*frcp(ny) * f;
    WRSPLIT(1, g*xa, g*xb)
  }
  WRSPLIT(2, xa, xb)
  { float n=fsqrt(h1sq+1e-15f); float g=fatanh(n)*frcp(n); WRSPLIT(3, g*h1a, g*h1b) }
  { float n=fsqrt(h2sq+1e-15f); float g=fatan(n)*frcp(n);  WRSPLIT(4, g*h2a, g*h2b) }
  WRSPLIT(5, h3a, h3b)
  { float n=fsqrt(c1sq+1e-15f); float g=fatanh(n)*frcp(n); WRSPLIT(6, g*c1a, g*c1b) }
  { float n=fsqrt(c2sq+1e-15f); float g=fatan(n)*frcp(n);  WRSPLIT(7, g*c2a, g*c2b) }
  WRSPLIT(8, c3a, c3b)
#undef WRSPLIT
}

// ---------------- MFMA bf16x3 GEMM with LDS-staged W ----------------
enum { P_ID=0, P_EXP_P, P_EXP_S, P_SIG, P_TANH, P_SIG_LOG_P, P_SIG_LOG_S,
       P_LOGSIG_P, P_LOGSIG_S, P_TANH_EXP_P, P_TANH_EXP_S };

struct JobM { const u16* Ah; const u16* Al; const u16* Wh; const u16* Wl;
              const float* b; float* out; int pitch; int post; };
struct JobTabM { JobM j[12]; };

#define GITERS 4   // row-tiles of 64 per block -> 32 blocks/job

__global__ __launch_bounds__(256) void k_gemmM(JobTabM tab){
  JobM jb = tab.j[blockIdx.y];
  // W fragments, fragment-contiguous: linear index = plane*2048 + t*256 + kk*64 + lane, x 16B = 64 KB
  __shared__ u16 Wlds[2*8*4*64*8];
  const int tid = threadIdx.x;
  // ---- stage W (hi+lo) into LDS in fragment order ----
  // decode MUST match read index: lane=c&63, kk=(c>>6)&3, t=(c>>8)&7, plane=(c>>11)&1
  for(int c = tid; c < 4096; c += 256){
    int lane_ = c & 63;
    int kk    = (c>>6)&3;
    int t     = (c>>8)&7;
    int plane = (c>>11)&1;
    const u16* src = (plane ? jb.Wl : jb.Wh)
                   + (size_t)(t*16 + (lane_&15))*128 + (lane_>>4)*8 + kk*32;
    *(uint4*)&Wlds[(size_t)c*8] = *(const uint4*)src;
  }
  const int lane = tid & 63;
  const int wave = tid >> 6;
  const int nn = lane & 15, quad = lane >> 4;
  float bias[8];
#pragma unroll
  for(int t=0;t<8;t++) bias[t] = jb.b[t*16+nn];
  __syncthreads();
#pragma unroll
  for(int it=0; it<GITERS; it++){
    const int row0 = (blockIdx.x*GITERS + it)*64 + wave*16;
    const u16* Ah = jb.Ah + (size_t)(row0+nn)*128 + quad*8;
    const u16* Al = jb.Al + (size_t)(row0+nn)*128 + quad*8;
    f32x4 acc[8];
#pragma unroll
    for(int t=0;t<8;t++) acc[t] = (f32x4){0.f,0.f,0.f,0.f};
#pragma unroll
    for(int kk=0;kk<4;kk++){
      short8 ah = *(const short8*)(Ah + kk*32);
      short8 al = *(const short8*)(Al + kk*32);
#pragma unroll
      for(int t=0;t<8;t++){
        short8 wh = *(const short8*)&Wlds[(((0*8 + t)*4 + kk)*64 + lane)*8];
        short8 wl = *(const short8*)&Wlds[(((1*8 + t)*4 + kk)*64 + lane)*8];
        acc[t] = __builtin_amdgcn_mfma_f32_16x16x32_bf16(ah, wh, acc[t], 0,0,0);
        acc[t] = __builtin_amdgcn_mfma_f32_16x16x32_bf16(al, wh, acc[t], 0,0,0);
        acc[t] = __builtin_amdgcn_mfma_f32_16x16x32_bf16(ah, wl, acc[t], 0,0,0);
      }
    }
#pragma unroll
    for(int r=0;r<4;r++){
      float v[8];
#pragma unroll
      for(int t=0;t<8;t++) v[t] = acc[t][r] + bias[t];
      float s2 = 0.f;
#pragma unroll
      for(int t=0;t<8;t++) s2 += v[t]*v[t];
      float nraw = hred16(s2);
      switch(jb.post){
        case P_ID: break;
        case P_EXP_P: {
          float n=fsqrt(nraw+1e-15f); float tt=ftanh(n); float f=fminf(tt,PMX)*frcp(n);
          for(int t=0;t<8;t++) v[t]*=f;
        } break;
        case P_EXP_S: {
          float n=fsqrt(nraw+1e-15f); float f=ftan(n)*frcp(n);
          for(int t=0;t<8;t++) v[t]*=f;
        } break;
        case P_SIG:
          for(int t=0;t<8;t++) v[t]=sigm(v[t]);
          break;
        case P_TANH:
          for(int t=0;t<8;t++) v[t]=ftanh(v[t]);
          break;
        case P_SIG_LOG_P: {
          float n=fsqrt(nraw+1e-15f); float tt=ftanh(n); float f=fminf(tt,PMX)*frcp(n);
          float z[8]; float zs=0.f;
          for(int t=0;t<8;t++){ z[t]=sigm(f*v[t]); zs+=z[t]*z[t]; }
          float zr=hred16(zs);
          float zn=fsqrt(zr+1e-15f);
          float g=fatanh(zn)*frcp(zn);
          for(int t=0;t<8;t++) v[t]=g*z[t];
        } break;
        case P_SIG_LOG_S: {
          float n=fsqrt(nraw+1e-15f); float f=ftan(n)*frcp(n);
          float z[8]; float zs=0.f;
          for(int t=0;t<8;t++){ z[t]=sigm(f*v[t]); zs+=z[t]*z[t]; }
          float zr=hred16(zs);
          float zn=fsqrt(zr+1e-15f);
          float g=fatan(zn)*frcp(zn);
          for(int t=0;t<8;t++) v[t]=g*z[t];
        } break;
        case P_LOGSIG_P: {
          float n=fsqrt(nraw+1e-15f); float tt=ftanh(n); float f=fminf(tt,PMX)*frcp(n);
          float ny=fsqrt(f*f*nraw+1e-15f);
          float g=fatanh(ny)*frcp(ny)*f;
          for(int t=0;t<8;t++) v[t]=sigm(g*v[t]);
        } break;
        case P_LOGSIG_S: {
          float n=fsqrt(nraw+1e-15f); float f=ftan(n)*frcp(n);
          float ny=fsqrt(f*f*nraw+1e-15f);
          float g=fatan(ny)*frcp(ny)*f;
          for(int t=0;t<8;t++) v[t]=sigm(g*v[t]);
        } break;
        case P_TANH_EXP_P: {
          float n=fsqrt(nraw+1e-15f); float tt=ftanh(n); float f=fminf(tt,PMX)*frcp(n);
          float ny=fsqrt(f*f*nraw+1e-15f);
          float g=fatanh(ny)*frcp(ny)*f;
          float T[8]; float Ts=0.f;
          for(int t=0;t<8;t++){ T[t]=ftanh(g*v[t]); Ts+=T[t]*T[t]; }
          float Tr=hred16(Ts);
          float Tn=fsqrt(Tr+1e-15f);
          float t2=ftanh(Tn); float f2=fminf(t2,PMX)*frcp(Tn);
          for(int t=0;t<8;t++) v[t]=f2*T[t];
        } break;
        case P_TANH_EXP_S: {
          float n=fsqrt(nraw+1e-15f); float f=ftan(n)*frcp(n);
          float ny=fsqrt(f*f*nraw+1e-15f);
          float g=fatan(ny)*frcp(ny)*f;
          float T[8]; float Ts=0.f;
          for(int t=0;t<8;t++){ T[t]=ftanh(g*v[t]); Ts+=T[t]*T[t]; }
          float Tr=hred16(Ts);
          float Tn=fsqrt(Tr+1e-15f);
          float f2=ftan(Tn)*frcp(Tn);
          for(int t=0;t<8;t++) v[t]=f2*T[t];
        } break;
      }
      float* orow = jb.out + (size_t)(row0 + quad*4 + r)*jb.pitch + nn;
#pragma unroll
      for(int t=0;t<8;t++) orow[t*16] = v[t];
    }
  }
}

// ---------------- kernel 3: per-unique-node elementwise (phase B) ----------------
__global__ __launch_bounds__(256) void k_phaseB(
  const float* __restrict__ h1,const float* __restrict__ h2,const float* __restrict__ h3,
  const float* __restrict__ c1,const float* __restrict__ c2,const float* __restrict__ c3,
  const float* __restrict__ del_t, const float* __restrict__ dsc,
  float* __restrict__ ws)
{
  const float* S1 = ws+9*NHS;  const float* S2 = ws+10*NHS; const float* S3 = ws+11*NHS;
  const float* F1 = ws+12*NHS; const float* F2 = ws+13*NHS; const float* F3 = ws+14*NHS;
  const float* Q1 = ws+15*NHS; const float* Q2 = ws+16*NHS; const float* Q3 = ws+17*NHS;
  float* H1P = ws+21*NHS; float* H1S = ws+22*NHS; float* H1E = ws+23*NHS;
  float* V1 = ws+24*NHS;  float* V2 = ws+25*NHS;  float* V3 = ws+26*NHS;
  float* y2p = ws+SCOFF; float* y2s = y2p+8192; float* d1 = y2p+16384; float* d2 = y2p+24576;

  int j = blockIdx.x*4 + (threadIdx.x>>6);
  int l = threadIdx.x&63;
  size_t i0 = (size_t)j*HD+l, i1 = i0+64;
  float h1a=h1[i0],h1b=h1[i1], h2a=h2[i0],h2b=h2[i1], h3a=h3[i0],h3b=h3[i1];
  float c1a=c1[i0],c1b=c1[i1], c2a=c2[i0],c2b=c2[i1], c3a=c3[i0],c3b=c3[i1];
  float s1a=S1[i0],s1b=S1[i1], s2a=S2[i0],s2b=S2[i1], s3a=S3[i0],s3b=S3[i1];
  float f1a=F1[i0],f1b=F1[i1], f2a=F2[i0],f2b=F2[i1], f3a=F3[i0],f3b=F3[i1];
  float q1a=Q1[i0],q1b=Q1[i1], q2a=Q2[i0],q2b=Q2[i1], q3a=Q3[i0],q3b=Q3[i1];
  float g = fdiv(dsc[0], del_t[j]+1.0f);

  float h1sq = wred(h1a*h1a+h1b*h1b); float n1 = fsqrt(h1sq+1e-15f);
  float h2sq = wred(h2a*h2a+h2b*h2b); float n2 = fsqrt(h2sq+1e-15f);
  float h3sq = wred(h3a*h3a+h3b*h3b); float n3 = fsqrt(h3sq+1e-15f);
  float w1a=s1a*h1a, w1b=s1b*h1b;
  float w2a=s2a*h2a, w2b=s2b*h2b;
  float w3a=s3a*h3a, w3b=s3b*h3b;
  float w1sq = wred(w1a*w1a+w1b*w1b); float nw1 = fsqrt(w1sq+1e-15f);
  float w2sq = wred(w2a*w2a+w2b*w2b); float nw2 = fsqrt(w2sq+1e-15f);
  float w3sq = wred(w3a*w3a+w3b*w3b); float nw3 = fsqrt(w3sq+1e-15f);

  // ---- h_1p
  float t1 = ftanh(nw1*frcp(n1) * fatanh(n1));
  float fp1 = fminf(t1,PMX)*frcp(nw1); float np1 = fminf(t1,PMX);
  float nu2 = fatan(n2);
  float ne2 = fminf(ftanh(nu2),PMX);
  float t2 = ftanh(nw2*frcp(n2) * fatanh(ne2));
  float fp2 = fminf(t2,PMX)*frcp(nw2); float np2 = fminf(t2,PMX);
  float ne3 = fminf(ftanh(n3),PMX);
  float t3 = ftanh(nw3*frcp(n3) * fatanh(ne3));
  float fp3 = fminf(t3,PMX)*frcp(nw3); float np3 = fminf(t3,PMX);
  {
    float lamA = 2.0f*frcp(1.0f-np1*np1), lamB = 2.0f*frcp(1.0f-np2*np2), lamC = 2.0f*frcp(1.0f-np3*np3);
    float dn = frcp(fmaxf(fabsf(lamA+lamB+lamC-3.0f), EPSF));
    float va = (lamA*fp1*w1a + lamB*fp2*w2a + lamC*fp3*w3a)*dn;
    float vb = (lamA*fp1*w1b + lamB*fp2*w2b + lamC*fp3*w3b)*dn;
    float vsq = wred(va*va+vb*vb); float nv = fsqrt(vsq+1e-15f);
    float tt = ftanh(0.5f*fatanh(nv)); float ff = 3.0f*fminf(tt,PMX)*frcp(nv);
    H1P[i0]=ff*va; H1P[i1]=ff*vb;
    if(l==0) y2p[j] = ff*ff*vsq;
  }
  // ---- h_1s
  float t2s, fs2;
  {
    float nx1s = ftan(fatanh(n1));
    float t1s = ftanh(nw1*frcp(n1) * fatanh(nx1s));
    float fs1 = fminf(t1s,PMX)*frcp(nw1); float ns1 = fminf(t1s,PMX);
    t2s = ftan(nw2*frcp(n2) * fatan(n2));
    fs2 = t2s*frcp(nw2);
    float nx3s = ftan(n3);
    float t3s = ftan(nw3*frcp(n3) * fatan(nx3s));
    float fs3 = t3s*frcp(nw3);
    float lA = 2.0f*frcp(1.0f-ns1*ns1), lB = 2.0f*frcp(1.0f-t2s*t2s), lC = 2.0f*frcp(1.0f-t3s*t3s);
    float dns = frcp(fmaxf(fabsf(lA+lB+lC-3.0f), EPSF));
    float vsa = (lA*fs1*w1a + lB*fs2*w2a + lC*fs3*w3a)*dns;
    float vsb = (lA*fs1*w1b + lB*fs2*w2b + lC*fs3*w3b)*dns;
    float vssq = wred(vsa*vsa+vsb*vsb); float nvs = fsqrt(vssq+1e-15f);
    float tts = ftan(0.5f*fatan(nvs)); float ffs = 3.0f*tts*frcp(nvs);
    H1S[i0]=ffs*vsa; H1S[i1]=ffs*vsb;
    if(l==0) y2s[j] = ffs*ffs*vssq;
  }
  // ---- h_1e
  {
    float ne1 = fsqrt(fp1*fp1*w1sq + 1e-15f);
    float ge1 = fatanh(ne1)*frcp(ne1);
    float n2s_ = fsqrt(fs2*fs2*w2sq + 1e-15f);
    float ge2 = fatan(n2s_)*frcp(n2s_);
    H1E[i0] = ge1*fp1*w1a + ge2*fs2*w2a + s3a*h3a;
    H1E[i1] = ge1*fp1*w1b + ge2*fs2*w2b + s3b*h3b;
  }
  float ng = fsqrt(g*g+1e-15f);
  // ---- Poincare cell
  {
    float q1sq = wred(q1a*q1a+q1b*q1b);
    float c1rs = wred(c1a*c1a+c1b*c1b);
    float dq1 = wred(q1a*c1a+q1b*c1b);
    float xy = -dq1;
    float aa = 1.0f+2.0f*xy+c1rs, bb = 1.0f-q1sq;
    float dd = frcp(safeden(1.0f+2.0f*xy+q1sq*c1rs));
    float m1a = (aa*(-q1a)+bb*c1a)*dd, m1b = (aa*(-q1b)+bb*c1b)*dd;
    float m1sq = (aa*aa*q1sq + 2.0f*aa*bb*xy + bb*bb*c1rs)*dd*dd;
    float mdq = (-aa*q1sq + bb*dq1)*dd;
    { float nm = fsqrt(m1sq+1e-15f);
      if(nm>PMX){ float sc=PMX*frcp(nm); m1a*=sc; m1b*=sc; m1sq*=sc*sc; mdq*=sc; } }
    float nwg = fsqrt(g*g*q1sq+1e-15f);
    float tg = ftanh(nwg*frcp(ng) * fatanh(ng));
    float fX = fminf(tg,PMX)*frcp(nwg) * g;
    float X2sq = fX*fX*q1sq;
    float xy2 = fX*mdq;
    float a2 = 1.0f+2.0f*xy2+X2sq, b2 = 1.0f-m1sq;
    float d2d = frcp(safeden(1.0f+2.0f*xy2+m1sq*X2sq));
    float ka = (a2*m1a + b2*fX*q1a)*d2d, kb = (a2*m1b + b2*fX*q1b)*d2d;
    float ksq = (a2*a2*m1sq + 2.0f*a2*b2*xy2 + b2*b2*X2sq)*d2d*d2d;
    { float nk0 = fsqrt(ksq+1e-15f);
      if(nk0>PMX){ float sc=PMX*frcp(nk0); ka*=sc; kb*=sc; ksq*=sc*sc; } }
    float nk = fsqrt(ksq+1e-15f);
    float wfa = f1a*ka, wfb = f1b*kb;
    float wfsq = wred(wfa*wfa+wfb*wfb); float nwf = fsqrt(wfsq+1e-15f);
    float tu = ftanh(nwf*frcp(nk) * fatanh(nk));
    float fu = fminf(tu,PMX)*frcp(nwf);
    float u1sq = fu*fu*wfsq;
    float lam = 2.0f*frcp(1.0f-u1sq);
    V1[i0]=lam*fu*wfa; V1[i1]=lam*fu*wfb;
    if(l==0) d1[j]=lam-1.0f;
  }
  // ---- Sphere cell
  {
    float q2sq = wred(q2a*q2a+q2b*q2b);
    float c2rs = wred(c2a*c2a+c2b*c2b);
    float dq2 = wred(q2a*c2a+q2b*c2b);
    float xy = -dq2;
    float aa = 1.0f-2.0f*xy-c2rs, bb = 1.0f+q2sq;
    float dd = frcp(safeden(1.0f-2.0f*xy+q2sq*c2rs));
    float ma = (aa*(-q2a)+bb*c2a)*dd, mb = (aa*(-q2b)+bb*c2b)*dd;
    float msq = (aa*aa*q2sq + 2.0f*aa*bb*xy + bb*bb*c2rs)*dd*dd;
    float mdq = (-aa*q2sq + bb*dq2)*dd;
    float nwg = fsqrt(g*g*q2sq+1e-15f);
    float tg = ftan(nwg*frcp(ng) * fatan(ng));
    float fX = tg*frcp(nwg) * g;
    float X2sq = fX*fX*q2sq;
    float xy2 = fX*mdq;
    float a2 = 1.0f-2.0f*xy2-X2sq, b2 = 1.0f+msq;
    float d2d = frcp(safeden(1.0f-2.0f*xy2+msq*X2sq));
    float ka = (a2*ma + b2*fX*q2a)*d2d, kb = (a2*mb + b2*fX*q2b)*d2d;
    float ksq = (a2*a2*msq + 2.0f*a2*b2*xy2 + b2*b2*X2sq)*d2d*d2d;
    float nk = fsqrt(ksq+1e-15f);
    float wfa = f2a*ka, wfb = f2b*kb;
    float wfsq = wred(wfa*wfa+wfb*wfb); float nwf = fsqrt(wfsq+1e-15f);
    float tu = ftan(nwf*frcp(nk) * fatan(nk));
    float fu = tu*frcp(nwf);
    float u2sq = fu*fu*wfsq;
    float lam = 2.0f*frcp(1.0f+u2sq);
    V2[i0]=lam*fu*wfa; V2[i1]=lam*fu*wfb;
    if(l==0) d2[j]=lam-1.0f;
  }
  // ---- Euclid cell
  {
    float kea = c3a + q3a*(g-1.0f), keb = c3b + q3b*(g-1.0f);
    V3[i0]=f3a*kea; V3[i1]=f3b*keb;
  }
}

// ---------------- kernel 4: attention + K-reductions ----------------
__global__ __launch_bounds__(256) void k_attn(
  const int* __restrict__ nbr, float* __restrict__ ws)
{
  const float* XP = ws+18*NHS; const float* XS = ws+19*NHS; const float* XE = ws+20*NHS;
  const float* H1P = ws+21*NHS; const float* H1S = ws+22*NHS; const float* H1E = ws+23*NHS;
  const float* V1 = ws+24*NHS; const float* V2 = ws+25*NHS; const float* V3 = ws+26*NHS;
  u16* LPh = (u16*)(ws+9*NHS);  u16* LPl = LPh + NHS;
  u16* LSh = (u16*)(ws+10*NHS); u16* LSl = LSh + NHS;
  u16* LEh = (u16*)(ws+11*NHS); u16* LEl = LEh + NHS;
  float* C1o = ws+12*NHS; float* C2o = ws+13*NHS; float* C3o = ws+14*NHS;
  const float* y2p = ws+SCOFF; const float* y2s = y2p+8192;
  const float* d1 = y2p+16384; const float* d2 = y2p+24576;
  float* c1n2 = (float*)(y2p+32768); float* c2n2 = (float*)(y2p+40960);

  int n = blockIdx.x*4 + (threadIdx.x>>6);
  int l = threadIdx.x&63;
  size_t i0 = (size_t)n*HD+l, i1 = i0+64;
  float XPa=XP[i0], XPb=XP[i1];
  float XSa=XS[i0], XSb=XS[i1];
  float XEa=XE[i0], XEb=XE[i1];
  float x2p = wred(XPa*XPa+XPb*XPb);
  float x2s = wred(XSa*XSa+XSb*XSb);
  float HPa[8],HPb[8],HSa[8],HSb[8],HEa[8],HEb[8],y2pk[8],y2sk[8];
  float scp[8],scs[8],sce[8];
  float v1a=0,v1b=0,v2a=0,v2b=0,v3a=0,v3b=0,ds1=0,ds2=0;
  const float rs = 0.08838834764831845f;
#pragma unroll
  for(int k=0;k<8;k++){
    int j = nbr[n*KNBR+k];
    size_t j0 = (size_t)j*HD+l, j1 = j0+64;
    HPa[k]=H1P[j0]; HPb[k]=H1P[j1];
    HSa[k]=H1S[j0]; HSb[k]=H1S[j1];
    HEa[k]=H1E[j0]; HEb[k]=H1E[j1];
    y2pk[k]=y2p[j]; y2sk[k]=y2s[j];
    v1a+=V1[j0]; v1b+=V1[j1];
    v2a+=V2[j0]; v2b+=V2[j1];
    v3a+=V3[j0]; v3b+=V3[j1];
    ds1+=d1[j]; ds2+=d2[j];
    float dp = wred(XPa*HPa[k]+XPb*HPb[k]);
    {
      float xy=-dp, y2=y2pk[k];
      float aa=1.0f+2.0f*xy+y2, bb=1.0f-x2p;
      float dd=frcp(safeden(1.0f+2.0f*xy+x2p*y2));
      float nsq=(aa*aa*x2p+2.0f*aa*bb*xy+bb*bb*y2)*dd*dd;
      float nn=fminf(fsqrt(nsq+1e-15f),PMX);
      scp[k] = -2.0f*fatanh(nn);
    }
    float dsv = wred(XSa*HSa[k]+XSb*HSb[k]);
    {
      float xy=-dsv, y2=y2sk[k];
      float aa=1.0f-2.0f*xy-y2, bb=1.0f+x2s;
      float dd=frcp(safeden(1.0f-2.0f*xy+x2s*y2));
      float nsq=(aa*aa*x2s+2.0f*aa*bb*xy+bb*bb*y2)*dd*dd;
      float nn=fsqrt(nsq+1e-15f);
      scs[k] = -2.0f*fatan(nn);
    }
    sce[k] = wred(XEa*HEa[k]+XEb*HEb[k])*rs;
  }
  { // p attention + wmid
    float mx=scp[0];
#pragma unroll
    for(int k=1;k<8;k++) mx=fmaxf(mx,scp[k]);
    float a[8]; float s=0;
#pragma unroll
    for(int k=0;k<8;k++){ a[k]=fexp(scp[k]-mx); s+=a[k]; }
    float inv=frcp(s);
    float na=0,nb=0,de=0;
#pragma unroll
    for(int k=0;k<8;k++){
      float lam = 2.0f*frcp(1.0f-y2pk[k]); float w=a[k]*inv;
      na+=w*lam*HPa[k]; nb+=w*lam*HPb[k]; de+=w*(lam-1.0f);
    }
    de = frcp(fmaxf(fabsf(de),EPSF));
    na*=de; nb*=de;
    float vsq=wred(na*na+nb*nb); float nv=fsqrt(vsq+1e-15f);
    float tt=ftanh(0.5f*fatanh(nv)); float f=fminf(tt,PMX)*frcp(nv);
    float ha=f*na, hb=f*nb;
    float hn=fsqrt(f*f*vsq+1e-15f);
    float gl=fatanh(hn)*frcp(hn);
    split2(gl*ha, &LPh[i0], &LPl[i0]); split2(gl*hb, &LPh[i1], &LPl[i1]);
  }
  { // s attention + wmid
    float mx=scs[0];
#pragma unroll
    for(int k=1;k<8;k++) mx=fmaxf(mx,scs[k]);
    float a[8]; float s=0;
#pragma unroll
    for(int k=0;k<8;k++){ a[k]=fexp(scs[k]-mx); s+=a[k]; }
    float inv=frcp(s);
    float na=0,nb=0,de=0;
#pragma unroll
    for(int k=0;k<8;k++){
      float lam = 2.0f*frcp(1.0f+y2sk[k]); float w=a[k]*inv;
      na+=w*lam*HSa[k]; nb+=w*lam*HSb[k]; de+=w*(lam-1.0f);
    }
    de = frcp(fmaxf(fabsf(de),EPSF));
    na*=de; nb*=de;
    float vsq=wred(na*na+nb*nb); float nv=fsqrt(vsq+1e-15f);
    float tt=ftan(0.5f*fatan(nv)); float f=tt*frcp(nv);
    float ha=f*na, hb=f*nb;
    float hn=fsqrt(f*f*vsq+1e-15f);
    float gl=fatan(hn)*frcp(hn);
    split2(gl*ha, &LSh[i0], &LSl[i0]); split2(gl*hb, &LSh[i1], &LSl[i1]);
  }
  { // e attention
    float mx=sce[0];
#pragma unroll
    for(int k=1;k<8;k++) mx=fmaxf(mx,sce[k]);
    float a[8]; float s=0;
#pragma unroll
    for(int k=0;k<8;k++){ a[k]=fexp(sce[k]-mx); s+=a[k]; }
    float inv=frcp(s);
    float ha=0,hb=0;
#pragma unroll
    for(int k=0;k<8;k++){ float w=a[k]*inv; ha+=w*HEa[k]; hb+=w*HEb[k]; }
    split2(ha, &LEh[i0], &LEl[i0]); split2(hb, &LEh[i1], &LEl[i1]);
  }
  { // c_1
    float de=frcp(fmaxf(fabsf(ds1),EPSF));
    float na=v1a*de, nb=v1b*de;
    float vsq=wred(na*na+nb*nb); float nv=fsqrt(vsq+1e-15f);
    float tt=ftanh(0.5f*fatanh(nv)); float f=fminf(tt,PMX)*frcp(nv);
    C1o[i0]=f*na; C1o[i1]=f*nb;
    if(l==0) c1n2[n]=f*f*vsq;
  }
  { // c_2
    float de=frcp(fmaxf(fabsf(ds2),EPSF));
    float na=v2a*de, nb=v2b*de;
    float vsq=wred(na*na+nb*nb); float nv=fsqrt(vsq+1e-15f);
    float tt=ftan(0.5f*fatan(nv)); float f=tt*frcp(nv);
    C2o[i0]=f*na; C2o[i1]=f*nb;
    if(l==0) c2n2[n]=f*f*vsq;
  }
  C3o[i0]=v3a; C3o[i1]=v3b;
}

// ---------------- kernel 6: final epilogue ----------------
__global__ __launch_bounds__(256) void k_final(
  const float* __restrict__ iou1, const float* __restrict__ iou2,
  const float* __restrict__ iou3, float* __restrict__ ws,
  float* __restrict__ out)
{
  const float* YP = ws; const float* YS = ws+3*NHS; const float* YE = ws+6*NHS;
  const float* C1v = ws+12*NHS; const float* C2v = ws+13*NHS; const float* C3v = ws+14*NHS;
  const float* c1n2 = ws+SCOFF+32768; const float* c2n2 = ws+SCOFF+40960;
  int n = blockIdx.x*4 + (threadIdx.x>>6);
  int l = threadIdx.x&63;
  size_t b384 = (size_t)n*384 + l;
  size_t b128 = (size_t)n*HD + l;
  // ================= Poincare =================
  {
    float Y[6], I[6];
#pragma unroll
    for(int r=0;r<6;r++){ Y[r]=YP[b384+64*r]; I[r]=iou1[b384+64*r]; }
    float sy=0,si=0,sx=0;
#pragma unroll
    for(int r=0;r<6;r++){ sy+=Y[r]*Y[r]; si+=I[r]*I[r]; sx+=I[r]*Y[r]; }
    sy=wred(sy); si=wred(si); sx=wred(sx);
    float nY=fsqrt(sy+1e-15f);
    float te=ftanh(nY); float fE=fminf(te,PMX)*frcp(nY);
    float y2=fE*fE*sy, x2=si, xy=fE*sx;
    float aa=1.0f+2.0f*xy+y2, bb=1.0f-x2;
    float dd=frcp(safeden(1.0f+2.0f*xy+x2*y2));
    float nio[6];
#pragma unroll
    for(int r=0;r<6;r++) nio[r]=(aa*I[r]+bb*fE*Y[r])*dd;
    float nsq=(aa*aa*x2+2.0f*aa*bb*xy+bb*bb*y2)*dd*dd;
    { float nn=fsqrt(nsq+1e-15f);
      if(nn>PMX){ float sc=PMX*frcp(nn); for(int r=0;r<6;r++) nio[r]*=sc; } }
    float ci=wred(nio[0]*nio[0]+nio[1]*nio[1]); float ni=fsqrt(ci+1e-15f); float gi=fatanh(ni)*frcp(ni);
    float ip0=sigm(gi*nio[0]), ip1=sigm(gi*nio[1]);
    float co=wred(nio[2]*nio[2]+nio[3]*nio[3]); float no=fsqrt(co+1e-15f); float go=fatanh(no)*frcp(no);
    float op0=sigm(go*nio[2]), op1=sigm(go*nio[3]);
    float cu=wred(nio[4]*nio[4]+nio[5]*nio[5]); float nu=fsqrt(cu+1e-15f); float gu=fatanh(nu)*frcp(nu);
    float up0=ftanh(gu*nio[4]), up1=ftanh(gu*nio[5]);
    float usq=wred(up0*up0+up1*up1); float nx=fsqrt(usq+1e-15f);
    float wv0=ip0*up0, wv1=ip1*up1;
    float wsq=wred(wv0*wv0+wv1*wv1); float nwx=fsqrt(wsq+1e-15f);
    float tP=ftanh(nwx*frcp(nx)*fatanh(nx)); float fP=fminf(tP,PMX)*frcp(nwx);
    float P0=fP*wv0, P1=fP*wv1; float p2=fP*fP*wsq;
    float ca=C1v[b128], cb=C1v[b128+64];
    float y2c=c1n2[n];
    float xyc=wred(P0*ca+P1*cb);
    float a3=1.0f+2.0f*xyc+y2c, b3=1.0f-p2;
    float d3=frcp(safeden(1.0f+2.0f*xyc+p2*y2c));
    float nc0=(a3*P0+b3*ca)*d3, nc1_=(a3*P1+b3*cb)*d3;
    float ncsq=(a3*a3*p2+2.0f*a3*b3*xyc+b3*b3*y2c)*d3*d3;
    { float nn=fsqrt(ncsq+1e-15f);
      if(nn>PMX){ float sc=PMX*frcp(nn); nc0*=sc; nc1_*=sc; ncsq*=sc*sc; } }
    float nl=fsqrt(ncsq+1e-15f);
    float gL=fatanh(nl)*frcp(nl);
    float T0=ftanh(gL*nc0), T1=ftanh(gL*nc1_);
    float tsq=wred(T0*T0+T1*T1); float nT=fsqrt(tsq+1e-15f);
    float wo0=op0*T0, wo1=op1*T1;
    float osq=wred(wo0*wo0+wo1*wo1); float nwo=fsqrt(osq+1e-15f);
    float tH=ftanh(nwo*frcp(nT)*fatanh(nT)); float fH=fminf(tH,PMX)*frcp(nwo);
    out[0*NHS + b128]=fH*wo0; out[0*NHS + b128+64]=fH*wo1;
    out[1*NHS + b128]=nc0;    out[1*NHS + b128+64]=nc1_;
  }
  // ================= Sphere =================
  {
    float Y[6], I[6];
#pragma unroll
    for(int r=0;r<6;r++){ Y[r]=YS[b384+64*r]; I[r]=iou2[b384+64*r]; }
    float sy=0,si=0,sx=0;
#pragma unroll
    for(int r=0;r<6;r++){ sy+=Y[r]*Y[r]; si+=I[r]*I[r]; sx+=I[r]*Y[r]; }
    sy=wred(sy); si=wred(si); sx=wred(sx);
    float nY=fsqrt(sy+1e-15f);
    float te=ftan(nY); float fE=te*frcp(nY);
    float y2=fE*fE*sy, x2=si, xy=fE*sx;
    float aa=1.0f-2.0f*xy-y2, bb=1.0f+x2;
    float dd=frcp(safeden(1.0f-2.0f*xy+x2*y2));
    float nio[6];
#pragma unroll
    for(int r=0;r<6;r++) nio[r]=(aa*I[r]+bb*fE*Y[r])*dd;
    float ci=wred(nio[0]*nio[0]+nio[1]*nio[1]); float ni=fsqrt(ci+1e-15f); float gi=fatan(ni)*frcp(ni);
    float ip0=sigm(gi*nio[0]), ip1=sigm(gi*nio[1]);
    float co=wred(nio[2]*nio[2]+nio[3]*nio[3]); float no=fsqrt(co+1e-15f); float go=fatan(no)*frcp(no);
    float op0=sigm(go*nio[2]), op1=sigm(go*nio[3]);
    float cu=wred(nio[4]*nio[4]+nio[5]*nio[5]); float nu=fsqrt(cu+1e-15f); float gu=fatan(nu)*frcp(nu);
    float up0=ftanh(gu*nio[4]), up1=ftanh(gu*nio[5]);
    float usq=wred(up0*up0+up1*up1); float nx=fsqrt(usq+1e-15f);
    float wv0=ip0*up0, wv1=ip1*up1;
    float wsq=wred(wv0*wv0+wv1*wv1); float nwx=fsqrt(wsq+1e-15f);
    float tP=ftan(nwx*frcp(nx)*fatan(nx)); float fP=tP*frcp(nwx);
    float P0=fP*wv0, P1=fP*wv1; float p2=fP*fP*wsq;
    float ca=C2v[b128], cb=C2v[b128+64];
    float y2c=c2n2[n];
    float xyc=wred(P0*ca+P1*cb);
    float a3=1.0f-2.0f*xyc-y2c, b3=1.0f+p2;
    float d3=frcp(safeden(1.0f-2.0f*xyc+p2*y2c));
    float nc0=(a3*P0+b3*ca)*d3, nc1_=(a3*P1+b3*cb)*d3;
    float ncsq=(a3*a3*p2+2.0f*a3*b3*xyc+b3*b3*y2c)*d3*d3;
    float nl=fsqrt(ncsq+1e-15f);
    float gL=fatan(nl)*frcp(nl);
    float T0=ftanh(gL*nc0), T1=ftanh(gL*nc1_);
    float tsq=wred(T0*T0+T1*T1); float nT=fsqrt(tsq+1e-15f);
    float wo0=op0*T0, wo1=op1*T1;
    float osq=wred(wo0*wo0+wo1*wo1); float nwo=fsqrt(osq+1e-15f);
    float tH=ftan(nwo*frcp(nT)*fatan(nT)); float fH=tH*frcp(nwo);
    out[2*NHS + b128]=fH*wo0; out[2*NHS + b128+64]=fH*wo1;
    out[3*NHS + b128]=nc0;    out[3*NHS + b128+64]=nc1_;
  }
  // ================= Euclid =================
  {
    float Y[6], I[6];
#pragma unroll
    for(int r=0;r<6;r++){ Y[r]=YE[b384+64*r]; I[r]=iou3[b384+64*r]; }
    float n0=I[0]+Y[0], n1=I[1]+Y[1];
    float n2=I[2]+Y[2], n3=I[3]+Y[3];
    float n4=I[4]+Y[4], n5=I[5]+Y[5];
    float ie0=sigm(n0), ie1=sigm(n1);
    float oe0=sigm(n2), oe1=sigm(n3);
    float ue0=ftanh(n4), ue1=ftanh(n5);
    float ca=C3v[b128], cb=C3v[b128+64];
    float nc0=ie0*ue0+ca, nc1_=ie1*ue1+cb;
    out[4*NHS + b128]=oe0*ftanh(nc0); out[4*NHS + b128+64]=oe1*ftanh(nc1_);
    out[5*NHS + b128]=nc0;            out[5*NHS + b128+64]=nc1_;
  }
}

extern "C" void kernel_launch(void* const* d_in, const int* in_sizes, int n_in,
                              void* d_out, int out_size, void* d_ws, size_t ws_size,
                              hipStream_t stream)
{
  const float* x     = (const float*)d_in[0];
  const float* h1    = (const float*)d_in[1];
  const float* c1    = (const float*)d_in[2];
  const float* h2    = (const float*)d_in[3];
  const float* c2    = (const float*)d_in[4];
  const float* h3    = (const float*)d_in[5];
  const float* c3    = (const float*)d_in[6];
  const float* del_t = (const float*)d_in[7];
  const float* iou1  = (const float*)d_in[8];
  const float* iou2  = (const float*)d_in[9];
  const float* iou3  = (const float*)d_in[10];
  const float* Wq_w  = (const float*)d_in[11];
  const float* Wq_b  = (const float*)d_in[12];
  const float* Wc_w  = (const float*)d_in[13];
  const float* Wc_b  = (const float*)d_in[14];
  const float* Uf_w  = (const float*)d_in[15];
  const float* Uf_b  = (const float*)d_in[16];
  const float* Up_w  = (const float*)d_in[17];
  const float* Up_b  = (const float*)d_in[18];
  const float* Uiou_w= (const float*)d_in[19];
  const float* Uiou_b= (const float*)d_in[20];
  const float* dsc   = (const float*)d_in[21];
  const int*   nbr   = (const int*)d_in[22];
  float* out = (float*)d_out;
  float* ws  = (float*)d_ws;

  k_wsplit<<<112,256,0,stream>>>(Wq_w,Wc_w,Uf_w,Up_w,Uiou_w,ws);
  k_pre<<<2048,256,0,stream>>>(x,h1,h2,c1,c2,h3,c3,ws);

  u16* WH = (u16*)(ws + WOFF);
  u16* WL = WH + NW;
  const u16* Wqh = WH;           const u16* Wql = WL;
  const u16* Wch = WH + 16384;   const u16* Wcl = WL + 16384;
  const u16* Ufh = WH + 32768;   const u16* Ufl = WL + 32768;
  const u16* Uph = WH + 49152;   const u16* Upl = WL + 49152;
  const u16* UIh = WH + 65536;   const u16* UIl = WL + 65536;
#define APLANE(R) ((const u16*)(ws + (size_t)(R)*NHS)), ((const u16*)(ws + (size_t)(R)*NHS) + NHS)

  JobTabM A{};
  A.j[0]  = { APLANE(0), Wqh, Wql, Wq_b, ws+18*NHS, 128, P_EXP_P };      // XP
  A.j[1]  = { APLANE(1), Wqh, Wql, Wq_b, ws+19*NHS, 128, P_EXP_S };      // XS
  A.j[2]  = { APLANE(2), Wqh, Wql, Wq_b, ws+20*NHS, 128, P_ID };         // XE
  A.j[3]  = { APLANE(3), Uph, Upl, Up_b, ws+9*NHS,  128, P_SIG_LOG_P };  // S1
  A.j[4]  = { APLANE(4), Uph, Upl, Up_b, ws+10*NHS, 128, P_SIG_LOG_S };  // S2
  A.j[5]  = { APLANE(5), Uph, Upl, Up_b, ws+11*NHS, 128, P_SIG };        // S3
  A.j[6]  = { APLANE(3), Ufh, Ufl, Uf_b, ws+12*NHS, 128, P_LOGSIG_P };   // F1
  A.j[7]  = { APLANE(4), Ufh, Ufl, Uf_b, ws+13*NHS, 128, P_LOGSIG_S };   // F2
  A.j[8]  = { APLANE(5), Ufh, Ufl, Uf_b, ws+14*NHS, 128, P_SIG };        // F3
  A.j[9]  = { APLANE(6), Wch, Wcl, Wc_b, ws+15*NHS, 128, P_TANH_EXP_P }; // CS1
  A.j[10] = { APLANE(7), Wch, Wcl, Wc_b, ws+16*NHS, 128, P_TANH_EXP_S }; // CS2
  A.j[11] = { APLANE(8), Wch, Wcl, Wc_b, ws+17*NHS, 128, P_TANH };       // CS3
  k_gemmM<<<dim3(NNODE/(GITERS*64),12),256,0,stream>>>(A);

  k_phaseB<<<2048,256,0,stream>>>(h1,h2,h3,c1,c2,c3,del_t,dsc,ws);
  k_attn<<<2048,256,0,stream>>>(nbr,ws);

  JobTabM B{};
  for(int ct=0; ct<3; ct++){
    B.j[0*3+ct] = { APLANE(9),  UIh + ct*16384, UIl + ct*16384, Uiou_b + ct*128, ws+0*NHS + ct*128, 384, P_ID };
    B.j[1*3+ct] = { APLANE(10), UIh + ct*16384, UIl + ct*16384, Uiou_b + ct*128, ws+3*NHS + ct*128, 384, P_ID };
    B.j[2*3+ct] = { APLANE(11), UIh + ct*16384, UIl + ct*16384, Uiou_b + ct*128, ws+6*NHS + ct*128, 384, P_ID };
  }
  k_gemmM<<<dim3(NNODE/(GITERS*64),9),256,0,stream>>>(B);

  k_final<<<2048,256,0,stream>>>(iou1,iou2,iou3,ws,out);
}